// Round 1
// baseline (354.408 us; speedup 1.0000x reference)
//
#include <hip/hip_runtime.h>
#include <hip/hip_bf16.h>
#include <stdint.h>

#define NH  16
#define SEQ 2048
#define DM  1024
#define HS  64
#define NB  4

typedef __attribute__((ext_vector_type(8))) short bf16x8;
typedef __attribute__((ext_vector_type(4))) float f32x4;

__device__ __forceinline__ unsigned short f2b(float f) {
    unsigned int u = __float_as_uint(f);
    u += 0x7fffu + ((u >> 16) & 1u);
    return (unsigned short)(u >> 16);
}

__device__ __forceinline__ void gload16(const void* g, void* lds) {
    __builtin_amdgcn_global_load_lds(
        (const __attribute__((address_space(1))) unsigned int*)g,
        (__attribute__((address_space(3))) unsigned int*)lds,
        16, 0, 0);
}

// ---------------- fp32 -> bf16 elementwise convert ----------------
__global__ void k_cvt(const float* __restrict__ in, unsigned short* __restrict__ out, int n) {
    int i = (blockIdx.x * blockDim.x + threadIdx.x) * 4;
    if (i >= n) return;
    float4 v = *(const float4*)(in + i);
    ushort4 o;
    o.x = f2b(v.x); o.y = f2b(v.y); o.z = f2b(v.z); o.w = f2b(v.w);
    *(ushort4*)(out + i) = o;
}

// ------------- fp32 [K][N] -> bf16 [N][K] transpose convert -------------
__global__ void k_tr(const float* __restrict__ in, unsigned short* __restrict__ out, int K, int N) {
    __shared__ float t[32][33];
    int n0 = blockIdx.x * 32, k0 = blockIdx.y * 32;
    int tx = threadIdx.x, ty = threadIdx.y;  // 32 x 8
#pragma unroll
    for (int j = 0; j < 32; j += 8)
        t[ty + j][tx] = in[(size_t)(k0 + ty + j) * N + n0 + tx];
    __syncthreads();
#pragma unroll
    for (int j = 0; j < 32; j += 8)
        out[(size_t)(n0 + ty + j) * K + k0 + tx] = f2b(t[tx][ty + j]);
}

// ---------------- bf16 GEMM: C = A[M][K] * Bt[N][K]^T + bias ----------------
// MODE 0: fp32 output [M][N] (+bias)
// MODE 1: qkv scatter: bf16 out [3][B*H][S][64], Q scaled by 0.125
template <int MODE>
__global__ __launch_bounds__(256, 2) void k_gemm(
    const unsigned short* __restrict__ A,
    const unsigned short* __restrict__ Bt,
    const float* __restrict__ bias,
    void* __restrict__ outp, int M, int N, int K)
{
    __shared__ unsigned short As[128 * 64];
    __shared__ unsigned short Bs[128 * 64];
    const int tid = threadIdx.x;
    const int l = tid & 63, w = tid >> 6;
    const int lg = l >> 4, li = l & 15;
    const int m0 = blockIdx.x * 128, n0 = blockIdx.y * 128;
    const int wm = (w >> 1) * 64, wn = (w & 1) * 64;

    f32x4 acc[4][4] = {};

    for (int k0 = 0; k0 < K; k0 += 64) {
        // stage A,B tiles: linear LDS dest, pre-swizzled global source (G21)
#pragma unroll
        for (int i = 0; i < 4; i++) {
            int ch = i * 256 + tid;        // 0..1023 chunk id (16B each)
            int row = ch >> 3, cc = ch & 7;
            int sc = cc ^ (row & 7);
            gload16(A + (size_t)(m0 + row) * K + k0 + sc * 8, &As[(i * 256 + w * 64) * 8]);
        }
#pragma unroll
        for (int i = 0; i < 4; i++) {
            int ch = i * 256 + tid;
            int row = ch >> 3, cc = ch & 7;
            int sc = cc ^ (row & 7);
            gload16(Bt + (size_t)(n0 + row) * K + k0 + sc * 8, &Bs[(i * 256 + w * 64) * 8]);
        }
        __syncthreads();
#pragma unroll
        for (int kc = 0; kc < 2; kc++) {
            bf16x8 af[4], bfr[4];
#pragma unroll
            for (int mi = 0; mi < 4; mi++) {
                int row = wm + mi * 16 + li;
                int chunk = (kc * 4 + lg) ^ (row & 7);
                af[mi] = *(const bf16x8*)&As[row * 64 + chunk * 8];
            }
#pragma unroll
            for (int ni = 0; ni < 4; ni++) {
                int row = wn + ni * 16 + li;
                int chunk = (kc * 4 + lg) ^ (row & 7);
                bfr[ni] = *(const bf16x8*)&Bs[row * 64 + chunk * 8];
            }
#pragma unroll
            for (int mi = 0; mi < 4; mi++)
#pragma unroll
                for (int ni = 0; ni < 4; ni++)
                    acc[mi][ni] = __builtin_amdgcn_mfma_f32_16x16x32_bf16(af[mi], bfr[ni], acc[mi][ni], 0, 0, 0);
        }
        __syncthreads();
    }

    // epilogue: D row = (l>>4)*4 + r, col = l&15  (m89 verified layout)
#pragma unroll
    for (int mi = 0; mi < 4; mi++) {
        int mrow = m0 + wm + mi * 16 + lg * 4;
#pragma unroll
        for (int ni = 0; ni < 4; ni++) {
            int col = n0 + wn + ni * 16 + li;
            float bv = bias[col];
            if (MODE == 0) {
                float* out = (float*)outp;
#pragma unroll
                for (int r = 0; r < 4; r++)
                    out[(size_t)(mrow + r) * N + col] = acc[mi][ni][r] + bv;
            } else {
                unsigned short* out = (unsigned short*)outp;
                int sqkv = col >> 10;
                int d = col & 1023;
                int h = d >> 6, c = d & 63;
                float scale = (sqkv == 0) ? 0.125f : 1.0f;
#pragma unroll
                for (int r = 0; r < 4; r++) {
                    int m = mrow + r;
                    int bq = m >> 11, sp = m & 2047;
                    size_t off = (size_t)sqkv * ((size_t)NB * NH * SEQ * HS) +
                                 ((size_t)(bq * NH + h) * SEQ + sp) * HS + c;
                    out[off] = f2b((acc[mi][ni][r] + bv) * scale);
                }
            }
        }
    }
}

// ---------------- causal flash attention ----------------
// qkv: [3][B*H][S][64] bf16 (Q pre-scaled by 1/8). ctx out: [B*S][1024] bf16
__global__ __launch_bounds__(256, 2) void k_attn(
    const unsigned short* __restrict__ qkv,
    unsigned short* __restrict__ ctx)
{
    __shared__ unsigned short Ks[64 * 64];
    __shared__ unsigned short Vt[64 * 64];
    __shared__ unsigned short Ps[4 * 16 * 64];
    const int tid = threadIdx.x;
    const int l = tid & 63, w = tid >> 6;
    const int lg = l >> 4, li = l & 15;
    const int bh = blockIdx.x;
    const int q0 = blockIdx.y * 64;
    const size_t hb = (size_t)bh * SEQ * HS;
    const size_t QKV1 = (size_t)NB * NH * SEQ * HS;  // 8388608
    const unsigned short* Qg = qkv + hb;
    const unsigned short* Kg = qkv + QKV1 + hb;
    const unsigned short* Vg = qkv + 2 * QKV1 + hb;

    // Q fragments (A operand: row = l&15, k = (l>>4)*8+j)
    bf16x8 aq[2];
    {
        int t = q0 + w * 16 + li;
        aq[0] = *(const bf16x8*)(Qg + (size_t)t * HS + lg * 8);
        aq[1] = *(const bf16x8*)(Qg + (size_t)t * HS + 32 + lg * 8);
    }

    f32x4 acc[4] = {};
    float mr[4] = {-1e30f, -1e30f, -1e30f, -1e30f};
    float ls[4] = {0.f, 0.f, 0.f, 0.f};
    const int ntiles = q0 / 64 + 1;

    for (int ft = 0; ft < ntiles; ft++) {
        int f0 = ft * 64;
        // stage K (swizzled source -> linear LDS)
#pragma unroll
        for (int i = 0; i < 2; i++) {
            int ch = i * 256 + tid;
            int row = ch >> 3, cc = ch & 7;
            int sc = cc ^ (row & 7);
            gload16(Kg + (size_t)(f0 + row) * HS + sc * 8, &Ks[(i * 256 + w * 64) * 8]);
        }
        // stage V transposed: Vt[c][f] with XOR swizzle on byte offset
#pragma unroll
        for (int i = 0; i < 2; i++) {
            int ch = i * 256 + tid;
            int fl = ch >> 3, c0 = (ch & 7) * 8;
            bf16x8 v = *(const bf16x8*)(Vg + (size_t)(f0 + fl) * HS + c0);
#pragma unroll
            for (int j = 0; j < 8; j++) {
                int c = c0 + j;
                int off = (c * 128 + fl * 2) ^ ((c & 7) << 4);
                *(unsigned short*)((char*)Vt + off) = ((unsigned short*)&v)[j];
            }
        }
        __syncthreads();

        // scores S = Q*K^T (Q pre-scaled): 16x16 tiles, B^T = K[f][c]
        f32x4 sa[4] = {};
#pragma unroll
        for (int kc = 0; kc < 2; kc++)
#pragma unroll
            for (int nt = 0; nt < 4; nt++) {
                int row = nt * 16 + li;
                int chunk = (kc * 4 + lg) ^ (row & 7);
                bf16x8 bk = *(const bf16x8*)&Ks[row * 64 + chunk * 8];
                sa[nt] = __builtin_amdgcn_mfma_f32_16x16x32_bf16(aq[kc], bk, sa[nt], 0, 0, 0);
            }

        // causal mask (only last tile can mask: f > t)
        if (ft == ntiles - 1) {
            int tb = q0 + w * 16 + lg * 4;
#pragma unroll
            for (int nt = 0; nt < 4; nt++) {
                int f = f0 + nt * 16 + li;
#pragma unroll
                for (int r = 0; r < 4; r++)
                    if (f > tb + r) sa[nt][r] = -1e30f;
            }
        }

        // online softmax (row spread over 16 lanes of group lg, 4 col-tiles)
        float corr[4];
#pragma unroll
        for (int r = 0; r < 4; r++) {
            float rm = fmaxf(fmaxf(sa[0][r], sa[1][r]), fmaxf(sa[2][r], sa[3][r]));
            rm = fmaxf(rm, __shfl_xor(rm, 1));
            rm = fmaxf(rm, __shfl_xor(rm, 2));
            rm = fmaxf(rm, __shfl_xor(rm, 4));
            rm = fmaxf(rm, __shfl_xor(rm, 8));
            float mn = fmaxf(mr[r], rm);
            corr[r] = __expf(mr[r] - mn);
            mr[r] = mn;
        }
        float rs[4] = {0.f, 0.f, 0.f, 0.f};
#pragma unroll
        for (int nt = 0; nt < 4; nt++)
#pragma unroll
            for (int r = 0; r < 4; r++) {
                float p = __expf(sa[nt][r] - mr[r]);
                sa[nt][r] = p;
                rs[r] += p;
            }
#pragma unroll
        for (int r = 0; r < 4; r++) {
            rs[r] += __shfl_xor(rs[r], 1);
            rs[r] += __shfl_xor(rs[r], 2);
            rs[r] += __shfl_xor(rs[r], 4);
            rs[r] += __shfl_xor(rs[r], 8);
            ls[r] = ls[r] * corr[r] + rs[r];
        }
#pragma unroll
        for (int nt = 0; nt < 4; nt++)
#pragma unroll
            for (int r = 0; r < 4; r++)
                acc[nt][r] *= corr[r];

        // P -> LDS (bf16, swizzled), per-wave region
#pragma unroll
        for (int nt = 0; nt < 4; nt++)
#pragma unroll
            for (int r = 0; r < 4; r++) {
                int row = lg * 4 + r, fl = nt * 16 + li;
                int off = (row * 128 + fl * 2) ^ ((row & 7) << 4);
                *(unsigned short*)((char*)Ps + w * 2048 + off) = f2b(sa[nt][r]);
            }
        __syncthreads();

        // PV: acc += P[16 x 64] * V[64 x 64]
#pragma unroll
        for (int kc = 0; kc < 2; kc++) {
            int pchunk = (kc * 4 + lg) ^ (li & 7);
            bf16x8 pf = *(const bf16x8*)((char*)Ps + w * 2048 + li * 128 + pchunk * 16);
#pragma unroll
            for (int nt = 0; nt < 4; nt++) {
                int c = nt * 16 + li;
                int vchunk = (kc * 4 + lg) ^ (c & 7);
                bf16x8 vf = *(const bf16x8*)((char*)Vt + c * 128 + vchunk * 16);
                acc[nt] = __builtin_amdgcn_mfma_f32_16x16x32_bf16(pf, vf, acc[nt], 0, 0, 0);
            }
        }
        __syncthreads();
    }

    // normalize + store ctx
    int b = bh >> 4, h = bh & 15;
#pragma unroll
    for (int nt = 0; nt < 4; nt++)
#pragma unroll
        for (int r = 0; r < 4; r++) {
            int t = q0 + w * 16 + lg * 4 + r;
            int c = nt * 16 + li;
            float v = acc[nt][r] / ls[r];
            ctx[((size_t)(b * SEQ + t)) * DM + h * HS + c] = f2b(v);
        }
}

extern "C" void kernel_launch(void* const* d_in, const int* in_sizes, int n_in,
                              void* d_out, int out_size, void* d_ws, size_t ws_size,
                              hipStream_t stream) {
    const float* enc    = (const float*)d_in[0];
    const float* w_attn = (const float*)d_in[1];
    const float* b_attn = (const float*)d_in[2];
    const float* w_proj = (const float*)d_in[3];
    const float* b_proj = (const float*)d_in[4];
    float* out = (float*)d_out;

    unsigned short* ws = (unsigned short*)d_ws;
    unsigned short* X    = ws;                       // [8192][1024] bf16 (reused as ctx)
    unsigned short* Wq   = ws + 8388608;             // [3072][1024] bf16
    unsigned short* Wp   = Wq + 3145728;             // [1024][1024] bf16
    unsigned short* QKV  = Wp + 1048576;             // [3][64][2048][64] bf16
    unsigned short* CTX  = X;                        // reuse (X dead after QKV GEMM)

    const int M = NB * SEQ;  // 8192

    k_cvt<<<8192, 256, 0, stream>>>(enc, X, M * DM);
    k_tr<<<dim3(96, 32), dim3(32, 8), 0, stream>>>(w_attn, Wq, DM, 3 * DM);
    k_tr<<<dim3(32, 32), dim3(32, 8), 0, stream>>>(w_proj, Wp, DM, DM);
    k_gemm<1><<<dim3(M / 128, 24), 256, 0, stream>>>(X, Wq, b_attn, QKV, M, 3 * DM, DM);
    k_attn<<<dim3(NB * NH, SEQ / 64), 256, 0, stream>>>(QKV, CTX);
    k_gemm<0><<<dim3(M / 128, 8), 256, 0, stream>>>(CTX, Wp, b_proj, out, M, DM, DM);
}

// Round 3
// 322.311 us; speedup vs baseline: 1.0996x; 1.0996x over previous
//
#include <hip/hip_runtime.h>
#include <hip/hip_bf16.h>
#include <stdint.h>

#define NH  16
#define SEQ 2048
#define DM  1024
#define HS  64
#define NB  4

typedef __attribute__((ext_vector_type(8))) short bf16x8;
typedef __attribute__((ext_vector_type(4))) float f32x4;

__device__ __forceinline__ unsigned short f2b(float f) {
    unsigned int u = __float_as_uint(f);
    u += 0x7fffu + ((u >> 16) & 1u);
    return (unsigned short)(u >> 16);
}

__device__ __forceinline__ void gload16(const void* g, void* lds) {
    __builtin_amdgcn_global_load_lds(
        (const __attribute__((address_space(1))) unsigned int*)g,
        (__attribute__((address_space(3))) unsigned int*)lds,
        16, 0, 0);
}

// ---------------- fp32 -> bf16 elementwise convert ----------------
__global__ void k_cvt(const float* __restrict__ in, unsigned short* __restrict__ out, int n) {
    int i = (blockIdx.x * blockDim.x + threadIdx.x) * 4;
    if (i >= n) return;
    float4 v = *(const float4*)(in + i);
    ushort4 o;
    o.x = f2b(v.x); o.y = f2b(v.y); o.z = f2b(v.z); o.w = f2b(v.w);
    *(ushort4*)(out + i) = o;
}

// ------------- fp32 [K][N] -> bf16 [N][K] transpose convert -------------
__global__ void k_tr(const float* __restrict__ in, unsigned short* __restrict__ out, int K, int N) {
    __shared__ float t[32][33];
    int n0 = blockIdx.x * 32, k0 = blockIdx.y * 32;
    int tx = threadIdx.x, ty = threadIdx.y;  // 32 x 8
#pragma unroll
    for (int j = 0; j < 32; j += 8)
        t[ty + j][tx] = in[(size_t)(k0 + ty + j) * N + n0 + tx];
    __syncthreads();
#pragma unroll
    for (int j = 0; j < 32; j += 8)
        out[(size_t)(n0 + ty + j) * K + k0 + tx] = f2b(t[tx][ty + j]);
}

// ---------------- bf16 GEMM: C = A[M][K] * Bt[N][K]^T + bias ----------------
// MODE 0: fp32 output [M][N] (+bias)
// MODE 1: qkv scatter: bf16 Q,K -> [B*H][S][64] (Q scaled 0.125); V -> [B*H][64][S] (transposed)
template <int MODE>
__global__ __launch_bounds__(256, 2) void k_gemm(
    const unsigned short* __restrict__ A,
    const unsigned short* __restrict__ Bt,
    const float* __restrict__ bias,
    void* __restrict__ outp, int M, int N, int K)
{
    __shared__ unsigned short As[128 * 64];
    __shared__ unsigned short Bs[128 * 64];
    const int tid = threadIdx.x;
    const int l = tid & 63, w = tid >> 6;
    const int lg = l >> 4, li = l & 15;
    const int m0 = blockIdx.x * 128, n0 = blockIdx.y * 128;
    const int wm = (w >> 1) * 64, wn = (w & 1) * 64;

    f32x4 acc[4][4] = {};

    for (int k0 = 0; k0 < K; k0 += 64) {
#pragma unroll
        for (int i = 0; i < 4; i++) {
            int ch = i * 256 + tid;        // 16B chunk id
            int row = ch >> 3, cc = ch & 7;
            int sc = cc ^ (row & 7);
            gload16(A + (size_t)(m0 + row) * K + k0 + sc * 8, &As[(i * 256 + w * 64) * 8]);
        }
#pragma unroll
        for (int i = 0; i < 4; i++) {
            int ch = i * 256 + tid;
            int row = ch >> 3, cc = ch & 7;
            int sc = cc ^ (row & 7);
            gload16(Bt + (size_t)(n0 + row) * K + k0 + sc * 8, &Bs[(i * 256 + w * 64) * 8]);
        }
        __syncthreads();
#pragma unroll
        for (int kc = 0; kc < 2; kc++) {
            bf16x8 af[4], bfr[4];
#pragma unroll
            for (int mi = 0; mi < 4; mi++) {
                int row = wm + mi * 16 + li;
                int chunk = (kc * 4 + lg) ^ (row & 7);
                af[mi] = *(const bf16x8*)&As[row * 64 + chunk * 8];
            }
#pragma unroll
            for (int ni = 0; ni < 4; ni++) {
                int row = wn + ni * 16 + li;
                int chunk = (kc * 4 + lg) ^ (row & 7);
                bfr[ni] = *(const bf16x8*)&Bs[row * 64 + chunk * 8];
            }
#pragma unroll
            for (int mi = 0; mi < 4; mi++)
#pragma unroll
                for (int ni = 0; ni < 4; ni++)
                    acc[mi][ni] = __builtin_amdgcn_mfma_f32_16x16x32_bf16(af[mi], bfr[ni], acc[mi][ni], 0, 0, 0);
        }
        __syncthreads();
    }

#pragma unroll
    for (int mi = 0; mi < 4; mi++) {
        int mrow = m0 + wm + mi * 16 + lg * 4;
#pragma unroll
        for (int ni = 0; ni < 4; ni++) {
            int col = n0 + wn + ni * 16 + li;
            float bv = bias[col];
            if (MODE == 0) {
                float* out = (float*)outp;
#pragma unroll
                for (int r = 0; r < 4; r++)
                    out[(size_t)(mrow + r) * N + col] = acc[mi][ni][r] + bv;
            } else {
                unsigned short* out = (unsigned short*)outp;
                const size_t QKV1 = (size_t)NB * NH * SEQ * HS;
                int sqkv = col >> 10;
                int d = col & 1023;
                int h = d >> 6, c = d & 63;
                float scale = (sqkv == 0) ? 0.125f : 1.0f;
#pragma unroll
                for (int r = 0; r < 4; r++) {
                    int m = mrow + r;
                    int bq = m >> 11, sp = m & 2047;
                    size_t off;
                    if (sqkv == 2)  // V transposed: [bh][c][S]
                        off = 2 * QKV1 + ((size_t)(bq * NH + h) * HS + c) * SEQ + sp;
                    else
                        off = (size_t)sqkv * QKV1 + ((size_t)(bq * NH + h) * SEQ + sp) * HS + c;
                    out[off] = f2b((acc[mi][ni][r] + bv) * scale);
                }
            }
        }
    }
}

// ---------------- causal flash attention ----------------
// qkv: Q,K [B*H][S][64] bf16 (Q pre-scaled 1/8); V^T [B*H][64][S] bf16.
// ctx out: [B*S][1024] bf16.  Block: 128 q rows, 4 waves x 2 row-tiles of 16.
__global__ __launch_bounds__(256) void k_attn(
    const unsigned short* __restrict__ qkv,
    unsigned short* __restrict__ ctx)
{
    __shared__ unsigned short Ks[64 * 64];
    __shared__ unsigned short Vts[64 * 64];
    __shared__ unsigned short Ps[4 * 32 * 64];  // 4KB per wave
    const int tid = threadIdx.x;
    const int l = tid & 63, w = tid >> 6;
    const int lg = l >> 4, li = l & 15;
    const int bh = blockIdx.x;
    const int q0 = (gridDim.y - 1 - blockIdx.y) * 128;  // long blocks first
    const size_t hb = (size_t)bh * SEQ * HS;
    const size_t QKV1 = (size_t)NB * NH * SEQ * HS;
    const unsigned short* Qg = qkv + hb;
    const unsigned short* Kg = qkv + QKV1 + hb;
    const unsigned short* VTg = qkv + 2 * QKV1 + hb;  // [64 c][2048 f]

    // Q fragments: A operand row = l&15, k = (l>>4)*8 + j
    bf16x8 aq[2][2];
#pragma unroll
    for (int rt = 0; rt < 2; rt++) {
        int t = q0 + rt * 64 + w * 16 + li;
        aq[rt][0] = *(const bf16x8*)(Qg + (size_t)t * HS + lg * 8);
        aq[rt][1] = *(const bf16x8*)(Qg + (size_t)t * HS + 32 + lg * 8);
    }

    f32x4 acc[2][4] = {};
    float mr[2][4], ls[2][4];
#pragma unroll
    for (int rt = 0; rt < 2; rt++)
#pragma unroll
        for (int r = 0; r < 4; r++) { mr[rt][r] = -1e30f; ls[rt][r] = 0.f; }

    const int ntiles = q0 / 64 + 2;

    for (int ft = 0; ft < ntiles; ft++) {
        int f0 = ft * 64;
        // stage K [f][c] and V^T [c][f]: linear LDS dest, pre-swizzled source
#pragma unroll
        for (int i = 0; i < 2; i++) {
            int ch = i * 256 + tid;
            int row = ch >> 3, cc = ch & 7;
            int sc = cc ^ (row & 7);
            gload16(Kg + (size_t)(f0 + row) * HS + sc * 8, &Ks[(i * 256 + w * 64) * 8]);
        }
#pragma unroll
        for (int i = 0; i < 2; i++) {
            int ch = i * 256 + tid;
            int row = ch >> 3, cc = ch & 7;
            int sc = cc ^ (row & 7);
            gload16(VTg + (size_t)row * SEQ + f0 + sc * 8, &Vts[(i * 256 + w * 64) * 8]);
        }
        __syncthreads();

#pragma unroll
        for (int rt = 0; rt < 2; rt++) {
            const int tb = q0 + rt * 64 + w * 16;  // first q row of this row-tile
            if (f0 > tb + 15) continue;            // fully masked (wave-uniform)

            // scores: S = Q*K^T
            f32x4 sa[4] = {};
#pragma unroll
            for (int kc = 0; kc < 2; kc++)
#pragma unroll
                for (int nt = 0; nt < 4; nt++) {
                    int row = nt * 16 + li;
                    int chunk = (kc * 4 + lg) ^ (row & 7);
                    bf16x8 bk = *(const bf16x8*)&Ks[row * 64 + chunk * 8];
                    sa[nt] = __builtin_amdgcn_mfma_f32_16x16x32_bf16(aq[rt][kc], bk, sa[nt], 0, 0, 0);
                }

            // causal mask (diagonal tile only)
            if (f0 + 63 > tb) {
                int trow = tb + lg * 4;
#pragma unroll
                for (int nt = 0; nt < 4; nt++) {
                    int f = f0 + nt * 16 + li;
#pragma unroll
                    for (int r = 0; r < 4; r++)
                        if (f > trow + r) sa[nt][r] = -1e30f;
                }
            }

            // online softmax: row = tb + lg*4 + r, spread over 16 li lanes
            float corr[4];
#pragma unroll
            for (int r = 0; r < 4; r++) {
                float rm = fmaxf(fmaxf(sa[0][r], sa[1][r]), fmaxf(sa[2][r], sa[3][r]));
                rm = fmaxf(rm, __shfl_xor(rm, 1));
                rm = fmaxf(rm, __shfl_xor(rm, 2));
                rm = fmaxf(rm, __shfl_xor(rm, 4));
                rm = fmaxf(rm, __shfl_xor(rm, 8));
                float mn = fmaxf(mr[rt][r], rm);
                corr[r] = __expf(mr[rt][r] - mn);
                mr[rt][r] = mn;
            }
            float rs[4] = {0.f, 0.f, 0.f, 0.f};
#pragma unroll
            for (int nt = 0; nt < 4; nt++)
#pragma unroll
                for (int r = 0; r < 4; r++) {
                    float p = __expf(sa[nt][r] - mr[rt][r]);
                    sa[nt][r] = p;
                    rs[r] += p;
                }
#pragma unroll
            for (int r = 0; r < 4; r++) {
                rs[r] += __shfl_xor(rs[r], 1);
                rs[r] += __shfl_xor(rs[r], 2);
                rs[r] += __shfl_xor(rs[r], 4);
                rs[r] += __shfl_xor(rs[r], 8);
                ls[rt][r] = ls[rt][r] * corr[r] + rs[r];
            }
#pragma unroll
            for (int nt = 0; nt < 4; nt++)
#pragma unroll
                for (int r = 0; r < 4; r++)
                    acc[rt][nt][r] *= corr[r];

            // P -> per-wave LDS region (XOR-swizzled rows), no barrier needed
            char* PB = (char*)Ps + w * 4096 + rt * 2048;
#pragma unroll
            for (int nt = 0; nt < 4; nt++)
#pragma unroll
                for (int r = 0; r < 4; r++) {
                    int row = lg * 4 + r, f = nt * 16 + li;
                    *(unsigned short*)(PB + row * 128 + ((f * 2) ^ ((row & 7) << 4))) = f2b(sa[nt][r]);
                }

            // PV: acc += P[16x64] * V[64x64]  (B operand = V^T rows)
#pragma unroll
            for (int kc = 0; kc < 2; kc++) {
                int C = kc * 4 + lg;
                bf16x8 pf = *(const bf16x8*)(PB + li * 128 + ((C * 16) ^ ((li & 7) << 4)));
#pragma unroll
                for (int nt = 0; nt < 4; nt++) {
                    int c = nt * 16 + li;
                    int vch = C ^ (c & 7);
                    bf16x8 vf = *(const bf16x8*)&Vts[c * 64 + vch * 8];
                    acc[rt][nt] = __builtin_amdgcn_mfma_f32_16x16x32_bf16(pf, vf, acc[rt][nt], 0, 0, 0);
                }
            }
        }
        __syncthreads();
    }

    // normalize + store
    int b = bh >> 4, h = bh & 15;
#pragma unroll
    for (int rt = 0; rt < 2; rt++)
#pragma unroll
        for (int nt = 0; nt < 4; nt++)
#pragma unroll
            for (int r = 0; r < 4; r++) {
                int t = q0 + rt * 64 + w * 16 + lg * 4 + r;
                int c = nt * 16 + li;
                float v = acc[rt][nt][r] / ls[rt][r];
                ctx[((size_t)(b * SEQ + t)) * DM + h * HS + c] = f2b(v);
            }
}

extern "C" void kernel_launch(void* const* d_in, const int* in_sizes, int n_in,
                              void* d_out, int out_size, void* d_ws, size_t ws_size,
                              hipStream_t stream) {
    const float* enc    = (const float*)d_in[0];
    const float* w_attn = (const float*)d_in[1];
    const float* b_attn = (const float*)d_in[2];
    const float* w_proj = (const float*)d_in[3];
    const float* b_proj = (const float*)d_in[4];
    float* out = (float*)d_out;

    unsigned short* ws = (unsigned short*)d_ws;
    unsigned short* X    = ws;                       // [8192][1024] bf16 (reused as ctx)
    unsigned short* Wq   = ws + 8388608;             // [3072][1024] bf16
    unsigned short* Wp   = Wq + 3145728;             // [1024][1024] bf16
    unsigned short* QKV  = Wp + 1048576;             // Q,K [64][2048][64]; V^T [64][64][2048]
    unsigned short* CTX  = X;                        // reuse (X dead after QKV GEMM)

    const int M = NB * SEQ;  // 8192

    k_cvt<<<8192, 256, 0, stream>>>(enc, X, M * DM);
    k_tr<<<dim3(96, 32), dim3(32, 8), 0, stream>>>(w_attn, Wq, DM, 3 * DM);
    k_tr<<<dim3(32, 32), dim3(32, 8), 0, stream>>>(w_proj, Wp, DM, DM);
    k_gemm<1><<<dim3(M / 128, 24), 256, 0, stream>>>(X, Wq, b_attn, QKV, M, 3 * DM, DM);
    k_attn<<<dim3(NB * NH, SEQ / 64 / 2), 256, 0, stream>>>(QKV, CTX);
    k_gemm<0><<<dim3(M / 128, 8), 256, 0, stream>>>(CTX, Wp, b_proj, out, M, DM, DM);
}

// Round 4
// 307.188 us; speedup vs baseline: 1.1537x; 1.0492x over previous
//
#include <hip/hip_runtime.h>
#include <hip/hip_bf16.h>
#include <stdint.h>

#define NH  16
#define SEQ 2048
#define DM  1024
#define HS  64
#define NB  4

typedef __attribute__((ext_vector_type(8))) short bf16x8;
typedef __attribute__((ext_vector_type(4))) float f32x4;

__device__ __forceinline__ unsigned short f2b(float f) {
    unsigned int u = __float_as_uint(f);
    u += 0x7fffu + ((u >> 16) & 1u);
    return (unsigned short)(u >> 16);
}

__device__ __forceinline__ void gload16(const void* g, void* lds) {
    __builtin_amdgcn_global_load_lds(
        (const __attribute__((address_space(1))) unsigned int*)g,
        (__attribute__((address_space(3))) unsigned int*)lds,
        16, 0, 0);
}

// ---------------- fp32 -> bf16 elementwise convert ----------------
__global__ void k_cvt(const float* __restrict__ in, unsigned short* __restrict__ out, int n) {
    int i = (blockIdx.x * blockDim.x + threadIdx.x) * 4;
    if (i >= n) return;
    float4 v = *(const float4*)(in + i);
    ushort4 o;
    o.x = f2b(v.x); o.y = f2b(v.y); o.z = f2b(v.z); o.w = f2b(v.w);
    *(ushort4*)(out + i) = o;
}

// ------------- fp32 [K][N] -> bf16 [N][K] transpose convert -------------
__global__ void k_tr(const float* __restrict__ in, unsigned short* __restrict__ out, int K, int N) {
    __shared__ float t[32][33];
    int n0 = blockIdx.x * 32, k0 = blockIdx.y * 32;
    int tx = threadIdx.x, ty = threadIdx.y;  // 32 x 8
#pragma unroll
    for (int j = 0; j < 32; j += 8)
        t[ty + j][tx] = in[(size_t)(k0 + ty + j) * N + n0 + tx];
    __syncthreads();
#pragma unroll
    for (int j = 0; j < 32; j += 8)
        out[(size_t)(n0 + ty + j) * K + k0 + tx] = f2b(t[tx][ty + j]);
}

// ---------------- bf16 GEMM: C = A[M][K] * Bt[N][K]^T + bias ----------------
// MODE 0: fp32 output [M][N] (+bias)
// MODE 1: qkv scatter: Q,K -> [B*H][S][64] (Q scaled 0.125*log2e); V -> [B*H][64][S]
template <int MODE>
__global__ __launch_bounds__(256, 2) void k_gemm(
    const unsigned short* __restrict__ A,
    const unsigned short* __restrict__ Bt,
    const float* __restrict__ bias,
    void* __restrict__ outp, int M, int N, int K)
{
    __shared__ unsigned short As[128 * 64];
    __shared__ unsigned short Bs[128 * 64];
    const int tid = threadIdx.x;
    const int l = tid & 63, w = tid >> 6;
    const int lg = l >> 4, li = l & 15;
    const int m0 = blockIdx.x * 128, n0 = blockIdx.y * 128;
    const int wm = (w >> 1) * 64, wn = (w & 1) * 64;

    f32x4 acc[4][4] = {};

    for (int k0 = 0; k0 < K; k0 += 64) {
#pragma unroll
        for (int i = 0; i < 4; i++) {
            int ch = i * 256 + tid;        // 16B chunk id
            int row = ch >> 3, cc = ch & 7;
            int sc = cc ^ (row & 7);
            gload16(A + (size_t)(m0 + row) * K + k0 + sc * 8, &As[(i * 256 + w * 64) * 8]);
        }
#pragma unroll
        for (int i = 0; i < 4; i++) {
            int ch = i * 256 + tid;
            int row = ch >> 3, cc = ch & 7;
            int sc = cc ^ (row & 7);
            gload16(Bt + (size_t)(n0 + row) * K + k0 + sc * 8, &Bs[(i * 256 + w * 64) * 8]);
        }
        __syncthreads();
#pragma unroll
        for (int kc = 0; kc < 2; kc++) {
            bf16x8 af[4], bfr[4];
#pragma unroll
            for (int mi = 0; mi < 4; mi++) {
                int row = wm + mi * 16 + li;
                int chunk = (kc * 4 + lg) ^ (row & 7);
                af[mi] = *(const bf16x8*)&As[row * 64 + chunk * 8];
            }
#pragma unroll
            for (int ni = 0; ni < 4; ni++) {
                int row = wn + ni * 16 + li;
                int chunk = (kc * 4 + lg) ^ (row & 7);
                bfr[ni] = *(const bf16x8*)&Bs[row * 64 + chunk * 8];
            }
#pragma unroll
            for (int mi = 0; mi < 4; mi++)
#pragma unroll
                for (int ni = 0; ni < 4; ni++)
                    acc[mi][ni] = __builtin_amdgcn_mfma_f32_16x16x32_bf16(af[mi], bfr[ni], acc[mi][ni], 0, 0, 0);
        }
        __syncthreads();
    }

#pragma unroll
    for (int mi = 0; mi < 4; mi++) {
        int mrow = m0 + wm + mi * 16 + lg * 4;
#pragma unroll
        for (int ni = 0; ni < 4; ni++) {
            int col = n0 + wn + ni * 16 + li;
            float bv = bias[col];
            if (MODE == 0) {
                float* out = (float*)outp;
#pragma unroll
                for (int r = 0; r < 4; r++)
                    out[(size_t)(mrow + r) * N + col] = acc[mi][ni][r] + bv;
            } else {
                unsigned short* out = (unsigned short*)outp;
                const size_t QKV1 = (size_t)NB * NH * SEQ * HS;
                int sqkv = col >> 10;
                int d = col & 1023;
                int h = d >> 6, c = d & 63;
                // Q scaled by 1/sqrt(hs) * log2(e) so attn can use exp2 directly
                float scale = (sqkv == 0) ? 0.18033688f : 1.0f;
#pragma unroll
                for (int r = 0; r < 4; r++) {
                    int m = mrow + r;
                    int bq = m >> 11, sp = m & 2047;
                    size_t off;
                    if (sqkv == 2)  // V transposed: [bh][c][S]
                        off = 2 * QKV1 + ((size_t)(bq * NH + h) * HS + c) * SEQ + sp;
                    else
                        off = (size_t)sqkv * QKV1 + ((size_t)(bq * NH + h) * SEQ + sp) * HS + c;
                    out[off] = f2b((acc[mi][ni][r] + bv) * scale);
                }
            }
        }
    }
}

// ---------------- causal flash attention ----------------
// qkv: Q,K [B*H][S][64] bf16 (Q pre-scaled 0.125*log2e); V^T [B*H][64][S] bf16.
// ctx out: [B*S][1024] bf16.
// Grid: (64 bh, 8). Block by handles q-tiles qa=by and qb=15-by (balanced causal
// pairing); qa's kv range is a prefix of qb's so staged K/V are shared.
// K/V double-buffered, stage issued before compute (latency hidden under compute).
__global__ __launch_bounds__(256, 2) void k_attn(
    const unsigned short* __restrict__ qkv,
    unsigned short* __restrict__ ctx)
{
    __shared__ unsigned short Ks[2][64 * 64];
    __shared__ unsigned short Vts[2][64 * 64];
    __shared__ unsigned short Ps[4 * 32 * 64];  // 4KB per wave
    const int tid = threadIdx.x;
    const int l = tid & 63, w = tid >> 6;
    const int lg = l >> 4, li = l & 15;
    const int bh = blockIdx.x;
    const int qa = blockIdx.y;        // 0..7
    const int qb = 15 - qa;
    const int qA0 = qa * 128, qB0 = qb * 128;
    const int na = qA0 / 64 + 2, nbt = qB0 / 64 + 2;
    const size_t hb = (size_t)bh * SEQ * HS;
    const size_t QKV1 = (size_t)NB * NH * SEQ * HS;
    const unsigned short* Qg = qkv + hb;
    const unsigned short* Kg = qkv + QKV1 + hb;
    const unsigned short* VTg = qkv + 2 * QKV1 + hb;  // [64 c][2048 f]

    // Q fragments: A operand row = l&15, k = (l>>4)*8 + j
    bf16x8 aqA[2][2], aqB[2][2];
#pragma unroll
    for (int rt = 0; rt < 2; rt++) {
        int tA = qA0 + rt * 64 + w * 16 + li;
        aqA[rt][0] = *(const bf16x8*)(Qg + (size_t)tA * HS + lg * 8);
        aqA[rt][1] = *(const bf16x8*)(Qg + (size_t)tA * HS + 32 + lg * 8);
        int tB = qB0 + rt * 64 + w * 16 + li;
        aqB[rt][0] = *(const bf16x8*)(Qg + (size_t)tB * HS + lg * 8);
        aqB[rt][1] = *(const bf16x8*)(Qg + (size_t)tB * HS + 32 + lg * 8);
    }

    f32x4 accA[2][4] = {}, accB[2][4] = {};
    float mrA[2][4], lsA[2][4], mrB[2][4], lsB[2][4];
#pragma unroll
    for (int rt = 0; rt < 2; rt++)
#pragma unroll
        for (int r = 0; r < 4; r++) {
            mrA[rt][r] = -1e30f; lsA[rt][r] = 0.f;
            mrB[rt][r] = -1e30f; lsB[rt][r] = 0.f;
        }

    auto stage = [&](int buf, int f0) {
#pragma unroll
        for (int i = 0; i < 2; i++) {
            int ch = i * 256 + tid;
            int row = ch >> 3, cc = ch & 7;
            int sc = cc ^ (row & 7);
            gload16(Kg + (size_t)(f0 + row) * HS + sc * 8, &Ks[buf][(i * 256 + w * 64) * 8]);
        }
#pragma unroll
        for (int i = 0; i < 2; i++) {
            int ch = i * 256 + tid;
            int row = ch >> 3, cc = ch & 7;
            int sc = cc ^ (row & 7);
            gload16(VTg + (size_t)row * SEQ + f0 + sc * 8, &Vts[buf][(i * 256 + w * 64) * 8]);
        }
    };

    auto process = [&](int q0, bf16x8 (&aq)[2][2], f32x4 (&acc)[2][4],
                       float (&mr)[2][4], float (&ls)[2][4], int f0, int buf) {
#pragma unroll
        for (int rt = 0; rt < 2; rt++) {
            const int tb = q0 + rt * 64 + w * 16;
            if (f0 > tb + 15) continue;  // fully masked (wave-uniform)

            // scores (log2-units): S = Q*K^T
            f32x4 sa[4] = {};
#pragma unroll
            for (int kc = 0; kc < 2; kc++)
#pragma unroll
                for (int nt = 0; nt < 4; nt++) {
                    int row = nt * 16 + li;
                    int chunk = (kc * 4 + lg) ^ (row & 7);
                    bf16x8 bk = *(const bf16x8*)&Ks[buf][row * 64 + chunk * 8];
                    sa[nt] = __builtin_amdgcn_mfma_f32_16x16x32_bf16(aq[rt][kc], bk, sa[nt], 0, 0, 0);
                }

            // causal mask (diagonal region only)
            if (f0 + 63 > tb) {
                int trow = tb + lg * 4;
#pragma unroll
                for (int nt = 0; nt < 4; nt++) {
                    int f = f0 + nt * 16 + li;
#pragma unroll
                    for (int r = 0; r < 4; r++)
                        if (f > trow + r) sa[nt][r] = -1e30f;
                }
            }

            // tile row max (rows spread over 16 li lanes)
            float pmax[4];
#pragma unroll
            for (int r = 0; r < 4; r++) {
                float rm = fmaxf(fmaxf(sa[0][r], sa[1][r]), fmaxf(sa[2][r], sa[3][r]));
                rm = fmaxf(rm, __shfl_xor(rm, 1));
                rm = fmaxf(rm, __shfl_xor(rm, 2));
                rm = fmaxf(rm, __shfl_xor(rm, 4));
                rm = fmaxf(rm, __shfl_xor(rm, 8));
                pmax[r] = rm;
            }
            // defer-max (T13): rescale only if max grew by >8 (log2 units)
            bool need = false;
#pragma unroll
            for (int r = 0; r < 4; r++) need |= (pmax[r] > mr[rt][r] + 8.0f);
            if (__any(need)) {
                float corr[4];
#pragma unroll
                for (int r = 0; r < 4; r++) {
                    float mn = fmaxf(mr[rt][r], pmax[r]);
                    corr[r] = __builtin_amdgcn_exp2f(mr[rt][r] - mn);
                    mr[rt][r] = mn;
                    ls[rt][r] *= corr[r];
                }
#pragma unroll
                for (int nt = 0; nt < 4; nt++)
#pragma unroll
                    for (int r = 0; r < 4; r++)
                        acc[rt][nt][r] *= corr[r];
            }

            float rs[4] = {0.f, 0.f, 0.f, 0.f};
#pragma unroll
            for (int nt = 0; nt < 4; nt++)
#pragma unroll
                for (int r = 0; r < 4; r++) {
                    float p = __builtin_amdgcn_exp2f(sa[nt][r] - mr[rt][r]);
                    sa[nt][r] = p;
                    rs[r] += p;
                }
#pragma unroll
            for (int r = 0; r < 4; r++) {
                rs[r] += __shfl_xor(rs[r], 1);
                rs[r] += __shfl_xor(rs[r], 2);
                rs[r] += __shfl_xor(rs[r], 4);
                rs[r] += __shfl_xor(rs[r], 8);
                ls[rt][r] += rs[r];
            }

            // P -> per-wave LDS region (truncate f32->bf16: 1 op, bias negligible)
            char* PB = (char*)Ps + w * 4096 + rt * 2048;
#pragma unroll
            for (int nt = 0; nt < 4; nt++)
#pragma unroll
                for (int r = 0; r < 4; r++) {
                    int row = lg * 4 + r, f = nt * 16 + li;
                    *(unsigned short*)(PB + row * 128 + ((f * 2) ^ ((row & 7) << 4))) =
                        (unsigned short)(__float_as_uint(sa[nt][r]) >> 16);
                }

            // PV: acc += P[16x64] * V[64x64]  (B operand = V^T rows)
#pragma unroll
            for (int kc = 0; kc < 2; kc++) {
                int C = kc * 4 + lg;
                bf16x8 pf = *(const bf16x8*)(PB + li * 128 + ((C * 16) ^ ((li & 7) << 4)));
#pragma unroll
                for (int nt = 0; nt < 4; nt++) {
                    int c = nt * 16 + li;
                    int vch = C ^ (c & 7);
                    bf16x8 vf = *(const bf16x8*)&Vts[buf][c * 64 + vch * 8];
                    acc[rt][nt] = __builtin_amdgcn_mfma_f32_16x16x32_bf16(pf, vf, acc[rt][nt], 0, 0, 0);
                }
            }
        }
    };

    stage(0, 0);
    __syncthreads();
    for (int ft = 0; ft < nbt; ft++) {
        int buf = ft & 1;
        if (ft + 1 < nbt) stage(buf ^ 1, (ft + 1) * 64);  // issue-early: hides HBM latency
        process(qB0, aqB, accB, mrB, lsB, ft * 64, buf);
        if (ft < na) process(qA0, aqA, accA, mrA, lsA, ft * 64, buf);
        __syncthreads();
    }

    // normalize + store both q-tiles
    int b = bh >> 4, h = bh & 15;
#pragma unroll
    for (int rt = 0; rt < 2; rt++)
#pragma unroll
        for (int nt = 0; nt < 4; nt++)
#pragma unroll
            for (int r = 0; r < 4; r++) {
                int c = nt * 16 + li;
                int tB = qB0 + rt * 64 + w * 16 + lg * 4 + r;
                ctx[((size_t)(b * SEQ + tB)) * DM + h * HS + c] = f2b(accB[rt][nt][r] / lsB[rt][r]);
                int tA = qA0 + rt * 64 + w * 16 + lg * 4 + r;
                ctx[((size_t)(b * SEQ + tA)) * DM + h * HS + c] = f2b(accA[rt][nt][r] / lsA[rt][r]);
            }
}

extern "C" void kernel_launch(void* const* d_in, const int* in_sizes, int n_in,
                              void* d_out, int out_size, void* d_ws, size_t ws_size,
                              hipStream_t stream) {
    const float* enc    = (const float*)d_in[0];
    const float* w_attn = (const float*)d_in[1];
    const float* b_attn = (const float*)d_in[2];
    const float* w_proj = (const float*)d_in[3];
    const float* b_proj = (const float*)d_in[4];
    float* out = (float*)d_out;

    unsigned short* ws = (unsigned short*)d_ws;
    unsigned short* X    = ws;                       // [8192][1024] bf16 (reused as ctx)
    unsigned short* Wq   = ws + 8388608;             // [3072][1024] bf16
    unsigned short* Wp   = Wq + 3145728;             // [1024][1024] bf16
    unsigned short* QKV  = Wp + 1048576;             // Q,K [64][2048][64]; V^T [64][64][2048]
    unsigned short* CTX  = X;                        // reuse (X dead after QKV GEMM)

    const int M = NB * SEQ;  // 8192

    k_cvt<<<8192, 256, 0, stream>>>(enc, X, M * DM);
    k_tr<<<dim3(96, 32), dim3(32, 8), 0, stream>>>(w_attn, Wq, DM, 3 * DM);
    k_tr<<<dim3(32, 32), dim3(32, 8), 0, stream>>>(w_proj, Wp, DM, DM);
    k_gemm<1><<<dim3(M / 128, 24), 256, 0, stream>>>(X, Wq, b_attn, QKV, M, 3 * DM, DM);
    k_attn<<<dim3(NB * NH, 8), 256, 0, stream>>>(QKV, CTX);
    k_gemm<0><<<dim3(M / 128, 8), 256, 0, stream>>>(CTX, Wp, b_proj, out, M, DM, DM);
}